// Round 8
// baseline (211.458 us; speedup 1.0000x reference)
//
#include <hip/hip_runtime.h>
#include <hip/hip_bf16.h>
#include <math.h>

typedef float v4f   __attribute__((ext_vector_type(4)));
typedef float f32x4 __attribute__((ext_vector_type(4)));
typedef short s16x8 __attribute__((ext_vector_type(8)));
typedef __hip_bfloat16 bf16;

#define PI_F 3.14159265358979323846f

// B=2, L=2048, D=256, K=32. Half-chunks: 16 rows, 128/batch, 256 total.
// Output chunks: 32 rows, 64/batch. Segments: 16 half-chunks, 8/batch.

__device__ inline unsigned short f2bf(float f) {
    unsigned int b = __float_as_uint(f);
    unsigned int r = (b + 0x7FFFu + ((b >> 16) & 1u)) >> 16;   // RNE
    return (unsigned short)r;
}
__device__ inline float bf2f(unsigned short u) {
    return __uint_as_float(((unsigned int)u) << 16);
}
__device__ inline void cvt8(const float* __restrict__ src, unsigned short* dst) {
    v4f a = *(const v4f*)src, b = *(const v4f*)(src + 4);
    ushort4 u0, u1;
    u0.x = f2bf(a[0]); u0.y = f2bf(a[1]); u0.z = f2bf(a[2]); u0.w = f2bf(a[3]);
    u1.x = f2bf(b[0]); u1.y = f2bf(b[1]); u1.z = f2bf(b[2]); u1.w = f2bf(b[3]);
    *(ushort4*)dst = u0; *(ushort4*)(dst + 4) = u1;
}

// Grid barrier. R7 post-mortem: spinning with atomicAdd(cnt,0) (an RMW)
// convoyed at the coherence point (~60us/barrier). Arrival stays an RMW;
// the SPIN is now a plain agent-scope atomic LOAD (loads are served
// concurrently by the LLC, no serialization) + longer s_sleep backoff.
// threadfence pair provides release/acquire for the non-atomic data
// (proven correct in R7).
__device__ inline void gridbar(int* cnt, int target) {
    __syncthreads();
    __threadfence();
    if (threadIdx.x == 0) {
        __hip_atomic_fetch_add(cnt, 1, __ATOMIC_RELAXED, __HIP_MEMORY_SCOPE_AGENT);
        while (__hip_atomic_load(cnt, __ATOMIC_RELAXED, __HIP_MEMORY_SCOPE_AGENT) < target)
            __builtin_amdgcn_s_sleep(16);
        __threadfence();
    }
    __syncthreads();
}

__global__ __launch_bounds__(512) void k_mega(
    const float* __restrict__ X,
    const float* __restrict__ kw1, const float* __restrict__ kb1,
    const float* __restrict__ kw2, const float* __restrict__ kb2,
    const float* __restrict__ qw1, const float* __restrict__ qb1,
    const float* __restrict__ qw2, const float* __restrict__ qb2,
    const float* __restrict__ vw,  const float* __restrict__ vb,
    float* __restrict__ KP, float* __restrict__ QP,
    float* __restrict__ PSR, float* __restrict__ PSI,
    bf16* __restrict__ Wb, bf16* __restrict__ W2b, bf16* __restrict__ Vb,
    bf16* __restrict__ SRg, bf16* __restrict__ SIg,
    float* __restrict__ out, int* __restrict__ bar)
{
    __shared__ __align__(16) unsigned char smem[74240];
    const int tid = threadIdx.x, bid = blockIdx.x;

    // ================= Phase 0: weight conversion (fp32 -> bf16) ==========
    {
        int gid = bid * 512 + tid;          // 832 rows * 32 groups-of-8
        if (gid < 26624) {
            int r = gid >> 5, c8 = (gid & 31) * 8;
            const float* src; unsigned short* dst;
            if (r < 768) {
                src = (r < 256) ? kw1 + (size_t)r * 256
                    : (r < 512) ? qw1 + (size_t)(r - 256) * 256
                                : vw  + (size_t)(r - 512) * 256;
                dst = (unsigned short*)Wb + (size_t)r * 256;
            } else {
                int r2 = r - 768;
                src = (r2 < 32) ? kw2 + (size_t)r2 * 256
                                : qw2 + (size_t)(r2 - 32) * 256;
                dst = (unsigned short*)W2b + (size_t)r2 * 256;
            }
            cvt8(src + c8, dst + c8);
        }
    }
    gridbar(bar + 0, 256);

    // ================= Phase 1: encode one 16-row half-chunk ==============
    {
        unsigned short* Abf = (unsigned short*)smem;            // [16][264]
        unsigned short* Hkq = (unsigned short*)(smem + 8448);   // [16][520]
        unsigned short* Vt  = (unsigned short*)(smem + 25088);  // [256][40] (t 16..31 zero)
        unsigned short* CKc = (unsigned short*)(smem + 45568);  // [32][40]
        unsigned short* CKs = (unsigned short*)(smem + 48128);  // [32][40]
        const int lane = tid & 63, wid = tid >> 6;              // 8 waves
        const int lrow = lane & 15, lk8 = (lane >> 4) * 8, t0 = (lane >> 4) * 4;
        const int bb = bid >> 7, hc = bid & 127;
        const int row0 = bb * 2048 + hc * 16;

        {   // stage X tile (16x256 fp32 -> bf16 LDS)
            int r = tid >> 5, c8 = (tid & 31) * 8;
            cvt8(X + (size_t)(row0 + r) * 256 + c8, &Abf[r * 264 + c8]);
        }
        {   // zero t=16..31 pads (GEMM3 runs K=32 over 16 real t rows)
            s16x8 z = {};
            { int r = tid >> 1, h = tid & 1; *(s16x8*)&Vt[r * 40 + 16 + h * 8] = z; }
            if (tid < 64)       { int r = tid >> 1, h = tid & 1;
                                  *(s16x8*)&CKc[r * 40 + 16 + h * 8] = z; }
            else if (tid < 128) { int r = (tid - 64) >> 1, h = tid & 1;
                                  *(s16x8*)&CKs[r * 40 + 16 + h * 8] = z; }
        }
        __syncthreads();

        // ---- GEMM1: wave owns 96 cols of [kw1|qw1|vw]^T ----
        const int nb = wid * 96;
        const unsigned short* Wu = (const unsigned short*)Wb;
        f32x4 acc[6] = {};
        for (int k0 = 0; k0 < 256; k0 += 32) {
            s16x8 a = *(const s16x8*)&Abf[lrow * 264 + k0 + lk8];
            #pragma unroll
            for (int nf = 0; nf < 6; ++nf) {
                s16x8 b = *(const s16x8*)(Wu + (size_t)(nb + nf * 16 + lrow) * 256 + k0 + lk8);
                acc[nf] = __builtin_amdgcn_mfma_f32_16x16x32_bf16(a, b, acc[nf], 0, 0, 0);
            }
        }
        // ---- epilogue: Hkq (tanh, bf16 LDS) / Vt (LDS) + Vb (global) ----
        #pragma unroll
        for (int nf = 0; nf < 6; ++nf) {
            int n = nb + nf * 16 + lrow;
            float bias = (n < 256) ? kb1[n] : (n < 512) ? qb1[n - 256] : vb[n - 512];
            if (n < 512) {
                #pragma unroll
                for (int r = 0; r < 4; ++r)
                    Hkq[(t0 + r) * 520 + n] = f2bf(tanhf(acc[nf][r] + bias));
            } else {
                int d = n - 512;
                ushort4 u;
                u.x = f2bf(acc[nf][0] + bias); u.y = f2bf(acc[nf][1] + bias);
                u.z = f2bf(acc[nf][2] + bias); u.w = f2bf(acc[nf][3] + bias);
                *(ushort4*)&Vt[d * 40 + t0] = u;
                unsigned short* Vg = (unsigned short*)Vb + (size_t)(row0 + t0) * 256 + d;
                Vg[0] = u.x; Vg[256] = u.y; Vg[512] = u.z; Vg[768] = u.w;
            }
        }
        __syncthreads();

        // ---- GEMM2 (waves 0-3): layer-2 + trig -> KP/QP global, CK LDS ----
        if (wid < 4) {
            const int which = wid >> 1, nf = wid & 1;
            const unsigned short* W2u = (const unsigned short*)W2b
                + (size_t)(which * 32 + nf * 16 + lrow) * 256;
            f32x4 u = {};
            for (int k0 = 0; k0 < 256; k0 += 32) {
                s16x8 a = *(const s16x8*)&Hkq[lrow * 520 + which * 256 + k0 + lk8];
                s16x8 b = *(const s16x8*)(W2u + k0 + lk8);
                u = __builtin_amdgcn_mfma_f32_16x16x32_bf16(a, b, u, 0, 0, 0);
            }
            const int outk = nf * 16 + lrow;
            const float bias = (which ? qb2 : kb2)[outk];
            float* dst = which ? QP : KP;
            float cs[4], sn[4];
            #pragma unroll
            for (int r = 0; r < 4; ++r) {
                float ph = tanhf(u[r] + bias) * PI_F;
                __sincosf(ph, &sn[r], &cs[r]);
                int row = row0 + t0 + r;
                dst[(size_t)row * 64 + outk]      = cs[r];
                dst[(size_t)row * 64 + 32 + outk] = sn[r];
            }
            if (which == 0) {
                ushort4 uc, us;
                uc.x = f2bf(cs[0]); uc.y = f2bf(cs[1]); uc.z = f2bf(cs[2]); uc.w = f2bf(cs[3]);
                us.x = f2bf(sn[0]); us.y = f2bf(sn[1]); us.z = f2bf(sn[2]); us.w = f2bf(sn[3]);
                *(ushort4*)&CKc[outk * 40 + t0] = uc;
                *(ushort4*)&CKs[outk * 40 + t0] = us;
            }
        }
        __syncthreads();

        // ---- GEMM3 (all 8 waves): half-chunk sums; wave owns 32 d-cols ----
        {
            f32x4 zz = {};
            s16x8 ac0 = *(const s16x8*)&CKc[lrow * 40 + lk8];
            s16x8 ac1 = *(const s16x8*)&CKc[(16 + lrow) * 40 + lk8];
            s16x8 as0 = *(const s16x8*)&CKs[lrow * 40 + lk8];
            s16x8 as1 = *(const s16x8*)&CKs[(16 + lrow) * 40 + lk8];
            unsigned short* SRu = (unsigned short*)SRg;
            unsigned short* SIu = (unsigned short*)SIg;
            #pragma unroll
            for (int nf = 0; nf < 2; ++nf) {
                int dcol = wid * 32 + nf * 16 + lrow;
                s16x8 bv = *(const s16x8*)&Vt[dcol * 40 + lk8];
                f32x4 r0 = __builtin_amdgcn_mfma_f32_16x16x32_bf16(ac0, bv, zz, 0, 0, 0);
                f32x4 r1 = __builtin_amdgcn_mfma_f32_16x16x32_bf16(ac1, bv, zz, 0, 0, 0);
                f32x4 i0 = __builtin_amdgcn_mfma_f32_16x16x32_bf16(as0, bv, zz, 0, 0, 0);
                f32x4 i1 = __builtin_amdgcn_mfma_f32_16x16x32_bf16(as1, bv, zz, 0, 0, 0);
                size_t base = (((size_t)(bb * 128 + hc)) * 32) * 256 + dcol;
                #pragma unroll
                for (int r = 0; r < 4; ++r) {
                    int ka = t0 + r, kb_ = 16 + t0 + r;
                    SRu[base + (size_t)ka  * 256] = f2bf(r0[r]);
                    SRu[base + (size_t)kb_ * 256] = f2bf(r1[r]);
                    SIu[base + (size_t)ka  * 256] = f2bf(i0[r]);
                    SIu[base + (size_t)kb_ * 256] = f2bf(i1[r]);
                }
            }
        }
    }
    gridbar(bar + 1, 256);

    // ================= Phase 2: segment partial sums ======================
    {
        int gid = bid * 512 + tid;                 // 131072 = 2b*8seg*2ri*4096
        int b = gid >> 16, rest = gid & 65535;
        int seg = rest >> 13, ri = (rest >> 12) & 1, e2 = rest & 4095;
        const unsigned short* S = (const unsigned short*)(ri ? SIg : SRg);
        float* PS = ri ? PSI : PSR;
        size_t base = ((size_t)(b * 128 + seg * 16)) * 8192 + e2 * 2;
        float s0 = 0.f, s1 = 0.f;
        #pragma unroll
        for (int j = 0; j < 16; ++j) {
            ushort2 u = *(const ushort2*)(S + base + (size_t)j * 8192);
            s0 += bf2f(u.x); s1 += bf2f(u.y);
        }
        size_t pb = ((size_t)(b * 8 + seg)) * 8192 + e2 * 2;
        PS[pb] = s0; PS[pb + 1] = s1;
    }
    gridbar(bar + 2, 256);

    // ================= Phase 3: output (one 32-row chunk, 2 dh slices) ====
    {
        float* QPc = (float*)smem;                  // [32][68] (shared, dup-written)
        float* KPc = QPc + 32 * 68;
        float* Sl  = KPc + 32 * 68;                 // [32][36]
        const int group = tid >> 8, t256 = tid & 255;
        float* grp  = Sl + 32 * 36 + group * (3 * 32 * 68);
        float* vall = grp;
        float* PRl  = grp + 32 * 68;
        float* PIl  = PRl + 32 * 68;
        const int b = bid >> 7, c = (bid >> 1) & 63, dhh = bid & 1;
        const int dh = dhh * 2 + group;
        const int row0 = b * 2048 + c * 32;

        #pragma unroll
        for (int it = 0; it < 2; ++it) {
            int idx = t256 + it * 256, t = idx >> 4, j4 = idx & 15;
            *(v4f*)&QPc[t * 68 + j4 * 4] = *(const v4f*)(QP + (size_t)(row0 + t) * 64 + j4 * 4);
            *(v4f*)&KPc[t * 68 + j4 * 4] = *(const v4f*)(KP + (size_t)(row0 + t) * 64 + j4 * 4);
        }
        {   // V slice bf16 -> fp32 LDS
            int t = t256 >> 3, e8 = (t256 & 7) * 8;
            s16x8 u = *(const s16x8*)((const unsigned short*)Vb
                                      + (size_t)(row0 + t) * 256 + dh * 64 + e8);
            #pragma unroll
            for (int j = 0; j < 8; ++j) vall[t * 68 + e8 + j] = bf2f((unsigned short)u[j]);
        }
        {   // exclusive-prefix reconstruction: PS segs + prior half-chunks
            int k = t256 >> 3, dg = t256 & 7;
            float pr[8] = {}, pi[8] = {};
            int hc0 = c * 2, seg = hc0 >> 4;
            for (int s = 0; s < seg; ++s) {
                size_t pb = ((size_t)(b * 8 + s)) * 8192 + k * 256 + dh * 64 + dg * 8;
                v4f r0 = *(const v4f*)(PSR + pb), r1 = *(const v4f*)(PSR + pb + 4);
                v4f i0 = *(const v4f*)(PSI + pb), i1 = *(const v4f*)(PSI + pb + 4);
                #pragma unroll
                for (int j = 0; j < 4; ++j) {
                    pr[j] += r0[j]; pr[4 + j] += r1[j];
                    pi[j] += i0[j]; pi[4 + j] += i1[j];
                }
            }
            for (int hp = seg * 16; hp < hc0; ++hp) {
                size_t sb = (((size_t)(b * 128 + hp)) * 32 + k) * 256 + dh * 64 + dg * 8;
                s16x8 ur = *(const s16x8*)((const unsigned short*)SRg + sb);
                s16x8 ui = *(const s16x8*)((const unsigned short*)SIg + sb);
                #pragma unroll
                for (int j = 0; j < 8; ++j) {
                    pr[j] += bf2f((unsigned short)ur[j]);
                    pi[j] += bf2f((unsigned short)ui[j]);
                }
            }
            #pragma unroll
            for (int j = 0; j < 8; ++j) {
                PRl[k * 68 + dg * 8 + j] = pr[j];
                PIl[k * 68 + dg * 8 + j] = pi[j];
            }
        }
        __syncthreads();
        {   // S tile (32x32 causal) — both groups compute identical values
            const int sl = t256 >> 3, tq = t256 & 7;
            float s4[4] = {0.f, 0.f, 0.f, 0.f};
            for (int j4 = 0; j4 < 16; ++j4) {
                v4f q4 = *(const v4f*)&QPc[sl * 68 + j4 * 4];
                #pragma unroll
                for (int i = 0; i < 4; ++i) {
                    v4f k4 = *(const v4f*)&KPc[(tq * 4 + i) * 68 + j4 * 4];
                    s4[i] += q4[0]*k4[0] + q4[1]*k4[1] + q4[2]*k4[2] + q4[3]*k4[3];
                }
            }
            #pragma unroll
            for (int i = 0; i < 4; ++i) {
                int t = tq * 4 + i;
                Sl[sl * 36 + t] = (t <= sl) ? s4[i] : 0.f;
            }
        }
        __syncthreads();
        const int l = t256 & 31, dq = t256 >> 5;
        const int d0 = dq * 8;
        float acc[8] = {};
        for (int k = 0; k < 32; ++k) {
            float qc = QPc[l * 68 + k], qs = QPc[l * 68 + 32 + k];
            #pragma unroll
            for (int j4 = 0; j4 < 2; ++j4) {
                v4f pr = *(const v4f*)&PRl[k * 68 + d0 + j4 * 4];
                v4f pi = *(const v4f*)&PIl[k * 68 + d0 + j4 * 4];
                #pragma unroll
                for (int x = 0; x < 4; ++x)
                    acc[j4 * 4 + x] += qc * pr[x] + qs * pi[x];
            }
        }
        for (int t = 0; t < 32; ++t) {
            float s = Sl[l * 36 + t];
            #pragma unroll
            for (int j4 = 0; j4 < 2; ++j4) {
                v4f v4_ = *(const v4f*)&vall[t * 68 + d0 + j4 * 4];
                #pragma unroll
                for (int x = 0; x < 4; ++x)
                    acc[j4 * 4 + x] = fmaf(s, v4_[x], acc[j4 * 4 + x]);
            }
        }
        const int gl = c * 32 + l;
        const float inv = rsqrtf((float)((gl + 1) * 32));
        const size_t ob = ((size_t)(b * 2048 + gl)) * 256 + dh * 64 + d0;
        #pragma unroll
        for (int j4 = 0; j4 < 2; ++j4) {
            v4f v;
            #pragma unroll
            for (int x = 0; x < 4; ++x) v[x] = acc[j4 * 4 + x] * inv;
            *(v4f*)(out + ob + j4 * 4) = v;
        }
    }
}

// ---------------------------------------------------------------------------
extern "C" void kernel_launch(void* const* d_in, const int* in_sizes, int n_in,
                              void* d_out, int out_size, void* d_ws, size_t ws_size,
                              hipStream_t stream)
{
    const float* x   = (const float*)d_in[0];
    const float* kw1 = (const float*)d_in[1];
    const float* kb1 = (const float*)d_in[2];
    const float* kw2 = (const float*)d_in[3];
    const float* kb2 = (const float*)d_in[4];
    const float* qw1 = (const float*)d_in[5];
    const float* qb1 = (const float*)d_in[6];
    const float* qw2 = (const float*)d_in[7];
    const float* qb2 = (const float*)d_in[8];
    const float* vw  = (const float*)d_in[9];
    const float* vb  = (const float*)d_in[10];
    float* out = (float*)d_out;

    char* ws = (char*)d_ws;
    int*   bar = (int*)ws;   ws += 256;
    float* KP  = (float*)ws; ws += (size_t)4096 * 64 * 4;
    float* QP  = (float*)ws; ws += (size_t)4096 * 64 * 4;
    float* PSR = (float*)ws; ws += (size_t)131072 * 4;
    float* PSI = (float*)ws; ws += (size_t)131072 * 4;
    bf16*  Wb  = (bf16*)ws;  ws += (size_t)768 * 256 * 2;
    bf16*  W2b = (bf16*)ws;  ws += (size_t)64 * 256 * 2;
    bf16*  Vb  = (bf16*)ws;  ws += (size_t)4096 * 256 * 2;
    bf16*  SRh = (bf16*)ws;  ws += (size_t)2 * 128 * 32 * 256 * 2;
    bf16*  SIh = (bf16*)ws;  ws += (size_t)2 * 128 * 32 * 256 * 2;

    hipMemsetAsync(bar, 0, 256, stream);
    k_mega<<<256, 512, 0, stream>>>(x, kw1, kb1, kw2, kb2, qw1, qb1, qw2, qb2,
                                    vw, vb, KP, QP, PSR, PSI, Wb, W2b, Vb,
                                    SRh, SIh, out, bar);
}

// Round 9
// 62.434 us; speedup vs baseline: 3.3869x; 3.3869x over previous
//
#include <hip/hip_runtime.h>
#include <hip/hip_bf16.h>
#include <math.h>

typedef float v4f   __attribute__((ext_vector_type(4)));
typedef float f32x4 __attribute__((ext_vector_type(4)));
typedef short s16x8 __attribute__((ext_vector_type(8)));
typedef __hip_bfloat16 bf16;

#define PI_F 3.14159265358979323846f

// B=2, L=2048, D=256, K=32. Half-chunks: 16 rows, 128/batch (encode grain).
// Output chunks: 32 rows, 64/batch. Scan segments: 8 chunks, 8/batch.
// PF[b][c][k][d] (bf16) = exclusive chunk-level prefix of sum(trig*value).

__device__ inline unsigned short f2bf(float f) {
    unsigned int b = __float_as_uint(f);
    unsigned int r = (b + 0x7FFFu + ((b >> 16) & 1u)) >> 16;   // RNE
    return (unsigned short)r;
}
__device__ inline float bf2f(unsigned short u) {
    return __uint_as_float(((unsigned int)u) << 16);
}
__device__ inline void cvt8(const float* __restrict__ src, unsigned short* dst) {
    v4f a = *(const v4f*)src, b = *(const v4f*)(src + 4);
    ushort4 u0, u1;
    u0.x = f2bf(a[0]); u0.y = f2bf(a[1]); u0.z = f2bf(a[2]); u0.w = f2bf(a[3]);
    u1.x = f2bf(b[0]); u1.y = f2bf(b[1]); u1.z = f2bf(b[2]); u1.w = f2bf(b[3]);
    *(ushort4*)dst = u0; *(ushort4*)(dst + 4) = u1;
}

// ---------------------------------------------------------------------------
// Kernel A: one-time weight conversion (proven R6 code).
// ---------------------------------------------------------------------------
__global__ __launch_bounds__(256) void k_cvtw(
    const float* __restrict__ kw1, const float* __restrict__ qw1,
    const float* __restrict__ vw,  const float* __restrict__ kw2,
    const float* __restrict__ qw2, bf16* __restrict__ Wb, bf16* __restrict__ W2b)
{
    int i8 = blockIdx.x * 256 + threadIdx.x;
    int r = i8 >> 5, c8 = (i8 & 31) * 8;
    const float* src;
    unsigned short* dst;
    if (r < 768) {
        src = (r < 256) ? kw1 + (size_t)r * 256
            : (r < 512) ? qw1 + (size_t)(r - 256) * 256
                        : vw  + (size_t)(r - 512) * 256;
        dst = (unsigned short*)Wb + (size_t)r * 256;
    } else {
        int r2 = r - 768;
        src = (r2 < 32) ? kw2 + (size_t)r2 * 256 : qw2 + (size_t)(r2 - 32) * 256;
        dst = (unsigned short*)W2b + (size_t)r2 * 256;
    }
    cvt8(src + c8, dst + c8);
}

// ---------------------------------------------------------------------------
// Kernel B: fused encode, one 16-row half-chunk per block (256 blocks, full
// chip). Proven as R7 phase 1. GEMM1 -> tanh/Hkq -> GEMM2+trig -> GEMM3
// half-chunk sums. Outputs: KP/QP fp32, Vb bf16, SRh/SIh bf16.
// ---------------------------------------------------------------------------
__global__ __launch_bounds__(512) void k_fused(
    const float* __restrict__ X,   const bf16* __restrict__ Wb,
    const float* __restrict__ kb1, const float* __restrict__ qb1,
    const float* __restrict__ vb,  const bf16* __restrict__ W2b,
    const float* __restrict__ kb2, const float* __restrict__ qb2,
    float* __restrict__ KP, float* __restrict__ QP,
    bf16* __restrict__ Vb, bf16* __restrict__ SRg, bf16* __restrict__ SIg)
{
    __shared__ __align__(16) unsigned char smem[50688];
    unsigned short* Abf = (unsigned short*)smem;            // [16][264]
    unsigned short* Hkq = (unsigned short*)(smem + 8448);   // [16][520]
    unsigned short* Vt  = (unsigned short*)(smem + 25088);  // [256][40] (t 16..31 zero)
    unsigned short* CKc = (unsigned short*)(smem + 45568);  // [32][40]
    unsigned short* CKs = (unsigned short*)(smem + 48128);  // [32][40]
    const int tid = threadIdx.x, bid = blockIdx.x;
    const int lane = tid & 63, wid = tid >> 6;              // 8 waves
    const int lrow = lane & 15, lk8 = (lane >> 4) * 8, t0 = (lane >> 4) * 4;
    const int bb = bid >> 7, hc = bid & 127;
    const int row0 = bb * 2048 + hc * 16;

    {   // stage X tile (16x256 fp32 -> bf16 LDS)
        int r = tid >> 5, c8 = (tid & 31) * 8;
        cvt8(X + (size_t)(row0 + r) * 256 + c8, &Abf[r * 264 + c8]);
    }
    {   // zero t=16..31 pads (GEMM3 runs K=32 over 16 real t rows)
        s16x8 z = {};
        { int r = tid >> 1, h = tid & 1; *(s16x8*)&Vt[r * 40 + 16 + h * 8] = z; }
        if (tid < 64)       { int r = tid >> 1, h = tid & 1;
                              *(s16x8*)&CKc[r * 40 + 16 + h * 8] = z; }
        else if (tid < 128) { int r = (tid - 64) >> 1, h = tid & 1;
                              *(s16x8*)&CKs[r * 40 + 16 + h * 8] = z; }
    }
    __syncthreads();

    // ---- GEMM1: wave owns 96 cols of [kw1|qw1|vw]^T ----
    const int nb = wid * 96;
    const unsigned short* Wu = (const unsigned short*)Wb;
    f32x4 acc[6] = {};
    for (int k0 = 0; k0 < 256; k0 += 32) {
        s16x8 a = *(const s16x8*)&Abf[lrow * 264 + k0 + lk8];
        #pragma unroll
        for (int nf = 0; nf < 6; ++nf) {
            s16x8 b = *(const s16x8*)(Wu + (size_t)(nb + nf * 16 + lrow) * 256 + k0 + lk8);
            acc[nf] = __builtin_amdgcn_mfma_f32_16x16x32_bf16(a, b, acc[nf], 0, 0, 0);
        }
    }
    // ---- epilogue: Hkq (tanh, bf16 LDS) / Vt (LDS) + Vb (global) ----
    #pragma unroll
    for (int nf = 0; nf < 6; ++nf) {
        int n = nb + nf * 16 + lrow;
        float bias = (n < 256) ? kb1[n] : (n < 512) ? qb1[n - 256] : vb[n - 512];
        if (n < 512) {
            #pragma unroll
            for (int r = 0; r < 4; ++r)
                Hkq[(t0 + r) * 520 + n] = f2bf(tanhf(acc[nf][r] + bias));
        } else {
            int d = n - 512;
            ushort4 u;
            u.x = f2bf(acc[nf][0] + bias); u.y = f2bf(acc[nf][1] + bias);
            u.z = f2bf(acc[nf][2] + bias); u.w = f2bf(acc[nf][3] + bias);
            *(ushort4*)&Vt[d * 40 + t0] = u;
            unsigned short* Vg = (unsigned short*)Vb + (size_t)(row0 + t0) * 256 + d;
            Vg[0] = u.x; Vg[256] = u.y; Vg[512] = u.z; Vg[768] = u.w;
        }
    }
    __syncthreads();

    // ---- GEMM2 (waves 0-3): layer-2 + trig -> KP/QP global, CK LDS ----
    if (wid < 4) {
        const int which = wid >> 1, nf = wid & 1;
        const unsigned short* W2u = (const unsigned short*)W2b
            + (size_t)(which * 32 + nf * 16 + lrow) * 256;
        f32x4 u = {};
        for (int k0 = 0; k0 < 256; k0 += 32) {
            s16x8 a = *(const s16x8*)&Hkq[lrow * 520 + which * 256 + k0 + lk8];
            s16x8 b = *(const s16x8*)(W2u + k0 + lk8);
            u = __builtin_amdgcn_mfma_f32_16x16x32_bf16(a, b, u, 0, 0, 0);
        }
        const int outk = nf * 16 + lrow;
        const float bias = (which ? qb2 : kb2)[outk];
        float* dst = which ? QP : KP;
        float cs[4], sn[4];
        #pragma unroll
        for (int r = 0; r < 4; ++r) {
            float ph = tanhf(u[r] + bias) * PI_F;
            __sincosf(ph, &sn[r], &cs[r]);
            int row = row0 + t0 + r;
            dst[(size_t)row * 64 + outk]      = cs[r];
            dst[(size_t)row * 64 + 32 + outk] = sn[r];
        }
        if (which == 0) {
            ushort4 uc, us;
            uc.x = f2bf(cs[0]); uc.y = f2bf(cs[1]); uc.z = f2bf(cs[2]); uc.w = f2bf(cs[3]);
            us.x = f2bf(sn[0]); us.y = f2bf(sn[1]); us.z = f2bf(sn[2]); us.w = f2bf(sn[3]);
            *(ushort4*)&CKc[outk * 40 + t0] = uc;
            *(ushort4*)&CKs[outk * 40 + t0] = us;
        }
    }
    __syncthreads();

    // ---- GEMM3 (all 8 waves): half-chunk sums; wave owns 32 d-cols ----
    {
        f32x4 zz = {};
        s16x8 ac0 = *(const s16x8*)&CKc[lrow * 40 + lk8];
        s16x8 ac1 = *(const s16x8*)&CKc[(16 + lrow) * 40 + lk8];
        s16x8 as0 = *(const s16x8*)&CKs[lrow * 40 + lk8];
        s16x8 as1 = *(const s16x8*)&CKs[(16 + lrow) * 40 + lk8];
        unsigned short* SRu = (unsigned short*)SRg;
        unsigned short* SIu = (unsigned short*)SIg;
        #pragma unroll
        for (int nf = 0; nf < 2; ++nf) {
            int dcol = wid * 32 + nf * 16 + lrow;
            s16x8 bv = *(const s16x8*)&Vt[dcol * 40 + lk8];
            f32x4 r0 = __builtin_amdgcn_mfma_f32_16x16x32_bf16(ac0, bv, zz, 0, 0, 0);
            f32x4 r1 = __builtin_amdgcn_mfma_f32_16x16x32_bf16(ac1, bv, zz, 0, 0, 0);
            f32x4 i0 = __builtin_amdgcn_mfma_f32_16x16x32_bf16(as0, bv, zz, 0, 0, 0);
            f32x4 i1 = __builtin_amdgcn_mfma_f32_16x16x32_bf16(as1, bv, zz, 0, 0, 0);
            size_t base = (((size_t)(bb * 128 + hc)) * 32) * 256 + dcol;
            #pragma unroll
            for (int r = 0; r < 4; ++r) {
                int ka = t0 + r, kb_ = 16 + t0 + r;
                SRu[base + (size_t)ka  * 256] = f2bf(r0[r]);
                SRu[base + (size_t)kb_ * 256] = f2bf(r1[r]);
                SIu[base + (size_t)ka  * 256] = f2bf(i0[r]);
                SIu[base + (size_t)kb_ * 256] = f2bf(i1[r]);
            }
        }
    }
}

// ---------------------------------------------------------------------------
// Kernel C: scan — materialize chunk-level EXCLUSIVE prefix PF (bf16).
// Thread owns (b, ri, seg of 8 chunks, e2 pair). Segment base computed
// redundantly per thread (<=112 coalesced L2-hot loads), then walks its 8
// chunks writing PF and accumulating the 2 half-chunk sums per chunk in fp32.
// ---------------------------------------------------------------------------
__global__ __launch_bounds__(512) void k_scan(
    const bf16* __restrict__ SRh, const bf16* __restrict__ SIh,
    bf16* __restrict__ PFR, bf16* __restrict__ PFI)
{
    int gid = blockIdx.x * 512 + threadIdx.x;    // 131072
    int e2 = gid & 4095, seg = (gid >> 12) & 7, ri = (gid >> 15) & 1, b = gid >> 16;
    const unsigned short* S = (const unsigned short*)(ri ? SIh : SRh);
    unsigned short* PF = (unsigned short*)(ri ? PFI : PFR);
    const size_t col = (size_t)e2 * 2;
    const size_t hbase = (size_t)(b * 128) * 8192 + col;
    float r0 = 0.f, r1 = 0.f;
    for (int hp = 0; hp < seg * 16; ++hp) {          // prior segments' halves
        ushort2 u = *(const ushort2*)(S + hbase + (size_t)hp * 8192);
        r0 += bf2f(u.x); r1 += bf2f(u.y);
    }
    #pragma unroll
    for (int j = 0; j < 8; ++j) {
        int c = seg * 8 + j;
        ushort2 w; w.x = f2bf(r0); w.y = f2bf(r1);
        *(ushort2*)(PF + (size_t)(b * 64 + c) * 8192 + col) = w;
        ushort2 u0 = *(const ushort2*)(S + hbase + (size_t)(2 * c)     * 8192);
        ushort2 u1 = *(const ushort2*)(S + hbase + (size_t)(2 * c + 1) * 8192);
        r0 += bf2f(u0.x) + bf2f(u1.x);
        r1 += bf2f(u0.y) + bf2f(u1.y);
    }
}

// ---------------------------------------------------------------------------
// Kernel D: output. 256 blocks x 512 thr; block = (b, chunk, dh-pair), two
// 256-thread groups each handle one 64-col dh slice. Prefix now a direct
// 16 KB PF read (was a 116 KB avg multi-tile walk — the R6 hidden cost).
// ---------------------------------------------------------------------------
__global__ __launch_bounds__(512) void k_attnout(
    const float* __restrict__ KP, const float* __restrict__ QP,
    const bf16* __restrict__ Vb,
    const bf16* __restrict__ PFR, const bf16* __restrict__ PFI,
    float* __restrict__ out)
{
    __shared__ float sm[18560];
    float* QPc = sm;                         // [32][68] (dup-written by groups)
    float* KPc = sm + 2176;
    float* Sl  = sm + 4352;                  // [32][36]
    const int tid = threadIdx.x, bid = blockIdx.x;
    const int group = tid >> 8, t256 = tid & 255;
    float* grp  = sm + 5504 + group * 6528;
    float* vall = grp;                       // [32][68]
    float* PRl  = grp + 2176;
    float* PIl  = grp + 4352;
    const int b = bid >> 7, c = (bid >> 1) & 63, dhh = bid & 1;
    const int dh = dhh * 2 + group;
    const int row0 = b * 2048 + c * 32;

    #pragma unroll
    for (int it = 0; it < 2; ++it) {
        int idx = t256 + it * 256, t = idx >> 4, j4 = idx & 15;
        *(v4f*)&QPc[t * 68 + j4 * 4] = *(const v4f*)(QP + (size_t)(row0 + t) * 64 + j4 * 4);
        *(v4f*)&KPc[t * 68 + j4 * 4] = *(const v4f*)(KP + (size_t)(row0 + t) * 64 + j4 * 4);
    }
    {   // V slice bf16 -> fp32 LDS
        int t = t256 >> 3, e8 = (t256 & 7) * 8;
        s16x8 u = *(const s16x8*)((const unsigned short*)Vb
                                  + (size_t)(row0 + t) * 256 + dh * 64 + e8);
        #pragma unroll
        for (int j = 0; j < 8; ++j) vall[t * 68 + e8 + j] = bf2f((unsigned short)u[j]);
    }
    {   // prefix state: direct PF read
        int k = t256 >> 3, dg = t256 & 7;
        size_t pb = ((size_t)(b * 64 + c)) * 8192 + k * 256 + dh * 64 + dg * 8;
        s16x8 ur = *(const s16x8*)((const unsigned short*)PFR + pb);
        s16x8 ui = *(const s16x8*)((const unsigned short*)PFI + pb);
        #pragma unroll
        for (int j = 0; j < 8; ++j) {
            PRl[k * 68 + dg * 8 + j] = bf2f((unsigned short)ur[j]);
            PIl[k * 68 + dg * 8 + j] = bf2f((unsigned short)ui[j]);
        }
    }
    __syncthreads();
    {   // S tile (32x32 causal) — both groups compute identical values
        const int sl = t256 >> 3, tq = t256 & 7;
        float s4[4] = {0.f, 0.f, 0.f, 0.f};
        for (int j4 = 0; j4 < 16; ++j4) {
            v4f q4 = *(const v4f*)&QPc[sl * 68 + j4 * 4];
            #pragma unroll
            for (int i = 0; i < 4; ++i) {
                v4f k4 = *(const v4f*)&KPc[(tq * 4 + i) * 68 + j4 * 4];
                s4[i] += q4[0]*k4[0] + q4[1]*k4[1] + q4[2]*k4[2] + q4[3]*k4[3];
            }
        }
        #pragma unroll
        for (int i = 0; i < 4; ++i) {
            int t = tq * 4 + i;
            Sl[sl * 36 + t] = (t <= sl) ? s4[i] : 0.f;
        }
    }
    __syncthreads();
    const int l = t256 & 31, dq = t256 >> 5;
    const int d0 = dq * 8;
    float acc[8] = {};
    for (int k = 0; k < 32; ++k) {
        float qc = QPc[l * 68 + k], qs = QPc[l * 68 + 32 + k];
        #pragma unroll
        for (int j4 = 0; j4 < 2; ++j4) {
            v4f pr = *(const v4f*)&PRl[k * 68 + d0 + j4 * 4];
            v4f pi = *(const v4f*)&PIl[k * 68 + d0 + j4 * 4];
            #pragma unroll
            for (int x = 0; x < 4; ++x)
                acc[j4 * 4 + x] += qc * pr[x] + qs * pi[x];
        }
    }
    for (int t = 0; t < 32; ++t) {
        float s = Sl[l * 36 + t];
        #pragma unroll
        for (int j4 = 0; j4 < 2; ++j4) {
            v4f v4_ = *(const v4f*)&vall[t * 68 + d0 + j4 * 4];
            #pragma unroll
            for (int x = 0; x < 4; ++x)
                acc[j4 * 4 + x] = fmaf(s, v4_[x], acc[j4 * 4 + x]);
        }
    }
    const int gl = c * 32 + l;
    const float inv = rsqrtf((float)((gl + 1) * 32));
    const size_t ob = ((size_t)(b * 2048 + gl)) * 256 + dh * 64 + d0;
    #pragma unroll
    for (int j4 = 0; j4 < 2; ++j4) {
        v4f v;
        #pragma unroll
        for (int x = 0; x < 4; ++x) v[x] = acc[j4 * 4 + x] * inv;
        *(v4f*)(out + ob + j4 * 4) = v;
    }
}

// ---------------------------------------------------------------------------
extern "C" void kernel_launch(void* const* d_in, const int* in_sizes, int n_in,
                              void* d_out, int out_size, void* d_ws, size_t ws_size,
                              hipStream_t stream)
{
    const float* x   = (const float*)d_in[0];
    const float* kw1 = (const float*)d_in[1];
    const float* kb1 = (const float*)d_in[2];
    const float* kw2 = (const float*)d_in[3];
    const float* kb2 = (const float*)d_in[4];
    const float* qw1 = (const float*)d_in[5];
    const float* qb1 = (const float*)d_in[6];
    const float* qw2 = (const float*)d_in[7];
    const float* qb2 = (const float*)d_in[8];
    const float* vw  = (const float*)d_in[9];
    const float* vb  = (const float*)d_in[10];
    float* out = (float*)d_out;

    char* ws = (char*)d_ws;
    float* KP  = (float*)ws; ws += (size_t)4096 * 64 * 4;
    float* QP  = (float*)ws; ws += (size_t)4096 * 64 * 4;
    bf16*  Wb  = (bf16*)ws;  ws += (size_t)768 * 256 * 2;
    bf16*  W2b = (bf16*)ws;  ws += (size_t)64 * 256 * 2;
    bf16*  Vb  = (bf16*)ws;  ws += (size_t)4096 * 256 * 2;
    bf16*  SRh = (bf16*)ws;  ws += (size_t)2 * 128 * 32 * 256 * 2;
    bf16*  SIh = (bf16*)ws;  ws += (size_t)2 * 128 * 32 * 256 * 2;
    bf16*  PFR = (bf16*)ws;  ws += (size_t)2 * 64 * 32 * 256 * 2;
    bf16*  PFI = (bf16*)ws;  ws += (size_t)2 * 64 * 32 * 256 * 2;

    k_cvtw   <<<104, 256, 0, stream>>>(kw1, qw1, vw, kw2, qw2, Wb, W2b);
    k_fused  <<<256, 512, 0, stream>>>(x, Wb, kb1, qb1, vb, W2b, kb2, qb2,
                                       KP, QP, Vb, SRh, SIh);
    k_scan   <<<256, 512, 0, stream>>>(SRh, SIh, PFR, PFI);
    k_attnout<<<256, 512, 0, stream>>>(KP, QP, Vb, PFR, PFI, out);
}